// Round 1
// baseline (1795.235 us; speedup 1.0000x reference)
//
#include <hip/hip_runtime.h>
#include <stdint.h>

#define L_SEQ 243
#define HID   256
#define CHK   81
#define NJ    17
#define NB    1088   // 64*17 sequences

typedef short bf16x8 __attribute__((ext_vector_type(8)));
typedef float f32x4  __attribute__((ext_vector_type(4)));

__device__ __forceinline__ unsigned short f2bf(float f) {
  unsigned int u = __float_as_uint(f);
  u = (u + 0x7fffu + ((u >> 16) & 1u)) >> 16;
  return (unsigned short)u;
}

// ---------------- ws layout (bytes) — unchanged from previous version ----------------
// Qw  bf16 [1088][243][256]           @ 0          (135,364,608)
// Kw  bf16 [1088][243][256]           @ 135364608
// Vt  bf16 [1088][256][248]  (pos-padded to 248)  @ 270729216  (138,149,888)
// Wt  bf16 [768][256]                 @ 408879104  (393,216)
// tables fp32 cu/su/cd/sd [243][128]  @ 409272320  (4*124,416)
// gpow fp32 [17][256]                 @ 409769984  (17,408)
#define OFF_Q   0ull
#define OFF_K   135364608ull
#define OFF_V   270729216ull
#define OFF_WT  408879104ull
#define OFF_TAB 409272320ull
#define OFF_GP  409769984ull
#define WS_NEED 409787392ull

// ---------------- kernel 1: precompute (unchanged) ----------------
__global__ void prep_kernel(const float* __restrict__ Wq, const float* __restrict__ Wk,
                            const float* __restrict__ Wv, const float* __restrict__ gamma,
                            unsigned short* __restrict__ Wt,
                            float* __restrict__ cu, float* __restrict__ su,
                            float* __restrict__ cd, float* __restrict__ sd,
                            float* __restrict__ gp) {
  int id = blockIdx.x * 256 + threadIdx.x;
  if (id < 768 * 256) {
    int n = id >> 8, k = id & 255;
    const float* W = (n < 256) ? Wq : (n < 512 ? Wk : Wv);
    Wt[n * 256 + k] = f2bf(W[k * 256 + (n & 255)]);
  } else if (id < 768 * 256 + L_SEQ * 128) {
    int r = id - 768 * 256;
    int p = r >> 7, h = r & 127;
    float base  = (2.0f * h + 102.4f) / 358.4f;          // (2h + 0.4*256)/(1.4*256)
    float scale = powf(base, (float)p * (1.0f / 512.0f));
    float invf  = powf(10000.0f, -(float)h * (1.0f / 128.0f));
    float ang   = (float)p * invf;
    float s, c; sincosf(ang, &s, &c);
    cu[p * 128 + h] = c * scale;  su[p * 128 + h] = s * scale;
    cd[p * 128 + h] = c / scale;  sd[p * 128 + h] = s / scale;
  } else if (id < 768 * 256 + L_SEQ * 128 + NJ * 256) {
    int r = id - (768 * 256 + L_SEQ * 128);
    int j = r >> 8, d = r & 255;
    gp[r] = (d < L_SEQ) ? powf(gamma[j], (float)d) : 0.0f;
  }
}

// ---------------- kernel 2: QKV projection + xpos ----------------
// v2: 64-row X tile (33.8KB LDS -> 4 blocks/CU), W fragments loaded DIRECTLY from
// global (L2-resident 393KB) -> no Ws staging, exactly ONE barrier per block.
// Wave layout: each wave covers all 64 m-rows x a 64-col n-slice; nt = {Q,K,V}.
__global__ __launch_bounds__(256, 4)
void proj_kernel(const float* __restrict__ X, const unsigned short* __restrict__ Wt,
                 const float* __restrict__ cu, const float* __restrict__ su,
                 const float* __restrict__ cd, const float* __restrict__ sd,
                 unsigned short* __restrict__ Qw, unsigned short* __restrict__ Kw,
                 unsigned short* __restrict__ Vt) {
  __shared__ __align__(16) unsigned short Xs[64 * 264];  // 64 rows x 256 k (+8 pad)
  int tid = threadIdx.x;
  int gid = blockIdx.x;
  int b = gid % NB, mt = gid / NB;
  int m0 = mt * 64;
  int wid = tid >> 6, lane = tid & 63, ln = lane & 15, quad = lane >> 4;
  const float* Xb = X + (size_t)b * (L_SEQ * HID);

  // stage X tile -> bf16 LDS (zero-pad rows >= 243); 8 floats/thread/iter
  #pragma unroll
  for (int it = 0; it < 8; ++it) {
    int idx = it * 256 + tid;
    int r = idx >> 5, seg = idx & 31;
    int p = m0 + r;
    float4 v0 = make_float4(0.f, 0.f, 0.f, 0.f), v1 = v0;
    if (p < L_SEQ) {
      v0 = *(const float4*)(Xb + p * HID + seg * 8);
      v1 = *(const float4*)(Xb + p * HID + seg * 8 + 4);
    }
    union { unsigned short u[8]; uint4 v; } pk;
    pk.u[0] = f2bf(v0.x); pk.u[1] = f2bf(v0.y); pk.u[2] = f2bf(v0.z); pk.u[3] = f2bf(v0.w);
    pk.u[4] = f2bf(v1.x); pk.u[5] = f2bf(v1.y); pk.u[6] = f2bf(v1.z); pk.u[7] = f2bf(v1.w);
    *(uint4*)&Xs[r * 264 + seg * 8] = pk.v;
  }
  __syncthreads();   // the ONLY barrier: Xs is read-only afterwards

  for (int nt = 0; nt < 3; ++nt) {   // nt: 0=Q, 1=K, 2=V (256 cols each)
    f32x4 acc[4][4] = {};
    int nb0 = nt * 256 + wid * 64;
    #pragma unroll
    for (int ks = 0; ks < 8; ++ks) {
      bf16x8 a[4], bw[4];
      #pragma unroll
      for (int j = 0; j < 4; ++j)   // B-fragment direct from global Wt[n][k] (L2-hot)
        bw[j] = *(const bf16x8*)(Wt + (nb0 + 16 * j + ln) * 256 + ks * 32 + quad * 8);
      #pragma unroll
      for (int i = 0; i < 4; ++i)
        a[i] = *(const bf16x8*)&Xs[(16 * i + ln) * 264 + ks * 32 + quad * 8];
      #pragma unroll
      for (int i = 0; i < 4; ++i)
        #pragma unroll
        for (int j = 0; j < 4; ++j)
          acc[i][j] = __builtin_amdgcn_mfma_f32_16x16x32_bf16(a[i], bw[j], acc[i][j], 0, 0, 0);
    }
    // epilogue: C/D layout col=lane&15, row=quad*4+reg (m89/m91-verified)
    if (nt < 2) {  // Q or K: xpos then row-major bf16 store
      const float* ct = (nt == 0) ? cu : cd;
      const float* st = (nt == 0) ? su : sd;
      unsigned short* Dst = (nt == 0) ? Qw : Kw;
      #pragma unroll
      for (int i = 0; i < 4; ++i) {
        int pb = m0 + 16 * i + quad * 4;
        #pragma unroll
        for (int j = 0; j < 4; ++j) {
          int d = wid * 64 + 16 * j + ln;
          int h = d >> 1;
          #pragma unroll
          for (int r = 0; r < 4; ++r) {
            float v  = acc[i][j][r];
            float pv = __shfl_xor(v, 1, 64);  // partner column d^1 lives in lane^1
            int p = pb + r;
            if (p < L_SEQ) {
              float c = ct[p * 128 + h], s = st[p * 128 + h];
              float o = (d & 1) ? (v * c + pv * s) : (v * c - pv * s);
              Dst[((size_t)b * L_SEQ + p) * 256 + d] = f2bf(o);
            }
          }
        }
      }
    } else {  // V: store transposed Vt[b][d][pos], pos stride 248; zero-fill pad rows 243..247
      #pragma unroll
      for (int i = 0; i < 4; ++i) {
        int p0 = m0 + 16 * i + quad * 4;
        #pragma unroll
        for (int j = 0; j < 4; ++j) {
          int d = wid * 64 + 16 * j + ln;
          size_t base = ((size_t)b * 256 + d) * 248 + p0;
          if (p0 + 3 < L_SEQ) {
            ushort4 pk;
            pk.x = f2bf(acc[i][j][0]); pk.y = f2bf(acc[i][j][1]);
            pk.z = f2bf(acc[i][j][2]); pk.w = f2bf(acc[i][j][3]);
            *(ushort4*)(Vt + base) = pk;   // 8B aligned: 248*2%8==0, p0%4==0
          } else if (p0 < 248) {
            #pragma unroll
            for (int r = 0; r < 4; ++r) {
              if (p0 + r < 248) {
                unsigned short val = (p0 + r < L_SEQ) ? f2bf(acc[i][j][r]) : (unsigned short)0;
                Vt[base + r] = val;
              }
            }
          }
        }
      }
    }
  }
}

// ---------------- kernel 3: decay-masked attention (linear, no softmax) ----------------
// v2: Q persistent in registers; K and V fragments loaded directly from global
// (row patterns give 64B-contiguous runs, L1/L2-served); P relayout via
// WAVE-PRIVATE LDS (DS ops are in-order within a wave) -> ZERO barriers in the
// main loop. Chunk mask -> qb blocks 0/1 only run 3/6 of 8 key-blocks.
__global__ __launch_bounds__(256, 3)
void attn_kernel(const unsigned short* __restrict__ Qw, const unsigned short* __restrict__ Kw,
                 const unsigned short* __restrict__ Vt, const float* __restrict__ gpow,
                 float* __restrict__ Out) {
  __shared__ __align__(16) unsigned short Ps[4 * 16 * 40];  // per-wave 16x32 P (+pad)
  __shared__ float gps[256];
  int tid = threadIdx.x;
  int gid = blockIdx.x;
  int b = gid % NB, qb = gid / NB;   // qblock-major: a seq's 4 blocks share an XCD (1088%8==0)
  int wid = tid >> 6, lane = tid & 63, ln = lane & 15, quad = lane >> 4;

  gps[tid] = gpow[(b % NJ) * 256 + tid];

  // Q -> registers, once. Row clamp (<=242) keeps pad lanes in-bounds; their
  // outputs are never stored.
  int qrow = qb * 64 + wid * 16 + ln;
  int qr = (qrow < L_SEQ) ? qrow : (L_SEQ - 1);
  const unsigned short* Qp = Qw + ((size_t)b * L_SEQ + qr) * 256 + quad * 8;
  bf16x8 aq[8];
  #pragma unroll
  for (int ks = 0; ks < 8; ++ks) aq[ks] = *(const bf16x8*)(Qp + ks * 32);

  int i0 = qb * 64 + wid * 16 + quad * 4;   // C-layout q-row base for this lane
  int lim[4];
  #pragma unroll
  for (int r = 0; r < 4; ++r) {
    int l = ((i0 + r) / CHK + 1) * CHK;
    lim[r] = (l > L_SEQ) ? L_SEQ : l;
  }
  int lmax = ((qb * 64 + 63) / CHK + 1) * CHK;
  if (lmax > L_SEQ) lmax = L_SEQ;
  int nkb = (lmax + 31) >> 5;     // qb=0:3, qb=1:6, qb>=2:8  (25/32 of full work)

  const unsigned short* Kb = Kw + (size_t)b * (L_SEQ * 256);
  const unsigned short* Vb = Vt + (size_t)b * (256 * 248);
  unsigned short* Pw = &Ps[wid * 640];   // wave-private region

  __syncthreads();   // gps visible to all waves; the ONLY barrier in the kernel

  f32x4 o[16] = {};
  for (int kb = 0; kb < nkb; ++kb) {
    int m0 = kb * 32;
    // ---- S = Q K^T (K fragments direct from global, row-clamped) ----
    int k0 = m0 + ln, k1 = m0 + 16 + ln;
    int kr0 = (k0 < L_SEQ) ? k0 : (L_SEQ - 1);
    int kr1 = (k1 < L_SEQ) ? k1 : (L_SEQ - 1);
    const unsigned short* Kp0 = Kb + (size_t)kr0 * 256 + quad * 8;
    const unsigned short* Kp1 = Kb + (size_t)kr1 * 256 + quad * 8;
    f32x4 s0 = {}, s1 = {};
    #pragma unroll
    for (int ks = 0; ks < 8; ++ks) {
      bf16x8 bk0 = *(const bf16x8*)(Kp0 + ks * 32);
      bf16x8 bk1 = *(const bf16x8*)(Kp1 + ks * 32);
      s0 = __builtin_amdgcn_mfma_f32_16x16x32_bf16(aq[ks], bk0, s0, 0, 0, 0);
      s1 = __builtin_amdgcn_mfma_f32_16x16x32_bf16(aq[ks], bk1, s1, 0, 0, 0);
    }
    // ---- decay in fp32, P -> bf16 -> wave-private LDS (no barrier: DS in-order per wave) ----
    #pragma unroll
    for (int t = 0; t < 2; ++t) {
      f32x4 sv = t ? s1 : s0;
      int m = m0 + t * 16 + ln;
      #pragma unroll
      for (int r = 0; r < 4; ++r) {
        int ad = i0 + r - m; ad = (ad < 0) ? -ad : ad;
        float f = (m < lim[r]) ? gps[ad] : 0.0f;   // gps[243..255]==0 covers pad
        Pw[(quad * 4 + r) * 40 + t * 16 + ln] = f2bf(sv[r] * f);
      }
    }
    bf16x8 ap = *(const bf16x8*)&Pw[ln * 40 + quad * 8];
    // ---- O += P V (V fragments direct from global Vt[d][pos]) ----
    const unsigned short* Vp = Vb + m0 + quad * 8;
    #pragma unroll
    for (int nt = 0; nt < 16; ++nt) {
      bf16x8 bv = *(const bf16x8*)(Vp + (nt * 16 + ln) * 248);
      o[nt] = __builtin_amdgcn_mfma_f32_16x16x32_bf16(ap, bv, o[nt], 0, 0, 0);
    }
  }
  // epilogue: fp32 store
  #pragma unroll
  for (int nt = 0; nt < 16; ++nt) {
    int d = nt * 16 + ln;
    #pragma unroll
    for (int r = 0; r < 4; ++r) {
      int p = qb * 64 + wid * 16 + quad * 4 + r;
      if (p < L_SEQ) Out[((size_t)b * L_SEQ + p) * 256 + d] = o[nt][r];
    }
  }
}

extern "C" void kernel_launch(void* const* d_in, const int* in_sizes, int n_in,
                              void* d_out, int out_size, void* d_ws, size_t ws_size,
                              hipStream_t stream) {
  const float* X     = (const float*)d_in[0];
  const float* Wq    = (const float*)d_in[1];
  const float* Wk    = (const float*)d_in[2];
  const float* Wv    = (const float*)d_in[3];
  const float* gamma = (const float*)d_in[4];
  if (ws_size < WS_NEED) return;  // deterministic guard (same work every call)

  char* ws = (char*)d_ws;
  unsigned short* Qw  = (unsigned short*)(ws + OFF_Q);
  unsigned short* Kw  = (unsigned short*)(ws + OFF_K);
  unsigned short* Vtw = (unsigned short*)(ws + OFF_V);
  unsigned short* Wt  = (unsigned short*)(ws + OFF_WT);
  float* cu = (float*)(ws + OFF_TAB);
  float* su = cu + L_SEQ * 128;
  float* cd = su + L_SEQ * 128;
  float* sd = cd + L_SEQ * 128;
  float* gp = (float*)(ws + OFF_GP);

  hipLaunchKernelGGL(prep_kernel, dim3(907), dim3(256), 0, stream,
                     Wq, Wk, Wv, gamma, Wt, cu, su, cd, sd, gp);
  hipLaunchKernelGGL(proj_kernel, dim3(4352), dim3(256), 0, stream,
                     X, Wt, cu, su, cd, sd, Qw, Kw, Vtw);
  hipLaunchKernelGGL(attn_kernel, dim3(4352), dim3(256), 0, stream,
                     Qw, Kw, Vtw, gp, (float*)d_out);
}

// Round 2
// 1465.721 us; speedup vs baseline: 1.2248x; 1.2248x over previous
//
#include <hip/hip_runtime.h>
#include <stdint.h>

#define L_SEQ 243
#define HID   256
#define CHK   81
#define NJ    17
#define NB    1088   // 64*17 sequences

typedef short bf16x8 __attribute__((ext_vector_type(8)));
typedef float f32x4  __attribute__((ext_vector_type(4)));

__device__ __forceinline__ unsigned short f2bf(float f) {
  unsigned int u = __float_as_uint(f);
  u = (u + 0x7fffu + ((u >> 16) & 1u)) >> 16;
  return (unsigned short)u;
}

// ---------------- ws layout (bytes) — offsets kept identical; Qw/Kw/Vt regions now unused
#define OFF_WT  408879104ull
#define OFF_TAB 409272320ull
#define OFF_GP  409769984ull
#define WS_NEED 409787392ull

// ---------------- kernel 1: precompute (unchanged) ----------------
__global__ void prep_kernel(const float* __restrict__ Wq, const float* __restrict__ Wk,
                            const float* __restrict__ Wv, const float* __restrict__ gamma,
                            unsigned short* __restrict__ Wt,
                            float* __restrict__ cu, float* __restrict__ su,
                            float* __restrict__ cd, float* __restrict__ sd,
                            float* __restrict__ gp) {
  int id = blockIdx.x * 256 + threadIdx.x;
  if (id < 768 * 256) {
    int n = id >> 8, k = id & 255;
    const float* W = (n < 256) ? Wq : (n < 512 ? Wk : Wv);
    Wt[n * 256 + k] = f2bf(W[k * 256 + (n & 255)]);
  } else if (id < 768 * 256 + L_SEQ * 128) {
    int r = id - 768 * 256;
    int p = r >> 7, h = r & 127;
    float base  = (2.0f * h + 102.4f) / 358.4f;          // (2h + 0.4*256)/(1.4*256)
    float scale = powf(base, (float)p * (1.0f / 512.0f));
    float invf  = powf(10000.0f, -(float)h * (1.0f / 128.0f));
    float ang   = (float)p * invf;
    float s, c; sincosf(ang, &s, &c);
    cu[p * 128 + h] = c * scale;  su[p * 128 + h] = s * scale;
    cd[p * 128 + h] = c / scale;  sd[p * 128 + h] = s / scale;
  } else if (id < 768 * 256 + L_SEQ * 128 + NJ * 256) {
    int r = id - (768 * 256 + L_SEQ * 128);
    int j = r >> 8, d = r & 255;
    gp[r] = (d < L_SEQ) ? powf(gamma[j], (float)d) : 0.0f;
  }
}

// ---------------- kernel 2: FUSED retention (proj + xpos + decay-attn) --------
// One block per sequence, 8 waves. Q lives in registers (A-frag layout) after a
// prologue GEMM with an LDS C->A bounce (wave-private rows, ds in-order, no
// barrier). Then 3 chunk iterations: stage X[81c..81c+96) -> compute K (xpos
// down) and V (transposed) into LDS -> masked QK / decay / PV. K and V never
// touch HBM. Chunk windows overlap by 15 rows; mask min(lim, 81(c+1)) ensures
// each key is counted exactly once (in its home chunk).
__global__ __launch_bounds__(512, 2)
void fused_kernel(const float* __restrict__ X, const unsigned short* __restrict__ Wt,
                  const float* __restrict__ cu, const float* __restrict__ su,
                  const float* __restrict__ cd, const float* __restrict__ sd,
                  const float* __restrict__ gpow, float* __restrict__ Out) {
  // u16 pool: Xs [96][264] @0 | Ks [96][264] @25344 | Vs [256][104] @50688.
  // Prologue aliases rows [0,256)x264 of the pool as the Q C->A bounce.
  // P bounce aliases Xs (dead after KV-GEMM) at wave-private offsets.
  __shared__ __align__(16) unsigned short SM[77312];   // 154,624 B
  __shared__ float gps[256];
  unsigned short* Xs = SM;
  unsigned short* Ks = SM + 25344;
  unsigned short* Vs = SM + 50688;

  const int tid = threadIdx.x;
  const int b = blockIdx.x;
  const int w = tid >> 6, lane = tid & 63, ln = lane & 15, quad = lane >> 4;
  const int rowbase = 32 * w;                 // wave owns q-rows [rowbase, rowbase+32)
  const float* Xb = X + (size_t)b * (L_SEQ * HID);

  if (tid < 256) gps[tid] = gpow[(b % NJ) * 256 + tid];

  // ---------------- prologue: Q = xpos(X @ Wq) -> qreg (A-frag layout) --------
  bf16x8 qreg[2][8];
  #pragma unroll
  for (int t = 0; t < 2; ++t) {
    // A-frags direct from global X: lane's row = rowbase+16t+ln (zero if padded)
    bf16x8 a[8];
    {
      int qrow = rowbase + 16 * t + ln;
      bool ok = (qrow < L_SEQ);
      const float* Xr = Xb + (size_t)(ok ? qrow : 0) * HID;
      #pragma unroll
      for (int ks = 0; ks < 8; ++ks) {
        f32x4 v0 = {}, v1 = {};
        if (ok) {
          v0 = __builtin_nontemporal_load((const f32x4*)(Xr + ks * 32 + quad * 8));
          v1 = __builtin_nontemporal_load((const f32x4*)(Xr + ks * 32 + quad * 8 + 4));
        }
        union { unsigned short u[8]; bf16x8 v; } pk;
        #pragma unroll
        for (int e = 0; e < 4; ++e) { pk.u[e] = f2bf(v0[e]); pk.u[4 + e] = f2bf(v1[e]); }
        a[ks] = pk.v;
      }
    }
    for (int j = 0; j < 16; ++j) {
      f32x4 acc = {};
      #pragma unroll
      for (int ks = 0; ks < 8; ++ks) {
        bf16x8 bw = *(const bf16x8*)(Wt + (size_t)(16 * j + ln) * 256 + ks * 32 + quad * 8);
        acc = __builtin_amdgcn_mfma_f32_16x16x32_bf16(a[ks], bw, acc, 0, 0, 0);
      }
      // xpos upscale; C layout col=ln(+16j), row=quad*4+r (m89/m91-verified)
      int d = 16 * j + ln, h = d >> 1;
      #pragma unroll
      for (int r = 0; r < 4; ++r) {
        float v = acc[r];
        float pv = __shfl_xor(v, 1, 64);       // partner column d^1 lives in lane^1
        int p = rowbase + 16 * t + quad * 4 + r;
        int tp = (p < L_SEQ) ? p : (L_SEQ - 1);
        float cc = cu[tp * 128 + h], ss = su[tp * 128 + h];
        float oq = (d & 1) ? (v * cc + pv * ss) : (v * cc - pv * ss);
        SM[(size_t)(rowbase + 16 * t + quad * 4 + r) * 264 + d] = f2bf(oq);
      }
    }
    // wave-local readback (ds ops in-order within a wave: no barrier needed)
    #pragma unroll
    for (int ks = 0; ks < 8; ++ks)
      qreg[t][ks] = *(const bf16x8*)&SM[(size_t)(rowbase + 16 * t + ln) * 264 + ks * 32 + quad * 8];
  }

  // wave attends key-chunk c iff floor(maxrow/81) >= c
  int cp1;
  { int mx = rowbase + 31; if (mx > L_SEQ - 1) mx = L_SEQ - 1; cp1 = mx / CHK; }

  f32x4 o[2][16] = {};
  unsigned short* Pw = Xs + w * 1280;   // 32 x 40 u16 wave-private P bounce (aliases dead Xs)

  __syncthreads();   // prologue scratch reads done; gps visible

  for (int c = 0; c < 3; ++c) {
    const int k0g = c * CHK;             // global base of this 96-row window
    __syncthreads();                     // A: all prev-chunk LDS reads done
    // ---- stage Xs rows [k0g, k0g+96), fp32 -> bf16, zero-pad past 242 ----
    #pragma unroll
    for (int it = 0; it < 6; ++it) {
      int idx = it * 512 + tid;          // 3072 = 96 rows * 32 segs
      int r = idx >> 5, seg = idx & 31;
      int p = k0g + r;
      f32x4 v0 = {}, v1 = {};
      if (p < L_SEQ) {
        v0 = __builtin_nontemporal_load((const f32x4*)(Xb + (size_t)p * HID + seg * 8));
        v1 = __builtin_nontemporal_load((const f32x4*)(Xb + (size_t)p * HID + seg * 8 + 4));
      }
      union { unsigned short u[8]; uint4 q; } pk;
      #pragma unroll
      for (int e = 0; e < 4; ++e) { pk.u[e] = f2bf(v0[e]); pk.u[4 + e] = f2bf(v1[e]); }
      *(uint4*)&Xs[(size_t)r * 264 + seg * 8] = pk.q;
    }
    __syncthreads();                     // B: Xs ready
    // ---- K and V chunk GEMMs; wave owns d-cols [32w, 32w+32) ----
    #pragma unroll
    for (int jj = 0; jj < 2; ++jj) {
      const int dn = 32 * w + 16 * jj + ln;
      const int hn = dn >> 1;
      bf16x8 bw[8];
      #pragma unroll
      for (int ks = 0; ks < 8; ++ks)
        bw[ks] = *(const bf16x8*)(Wt + (size_t)(256 + dn) * 256 + ks * 32 + quad * 8);
      for (int mk = 0; mk < 6; ++mk) {
        f32x4 acc = {};
        #pragma unroll
        for (int ks = 0; ks < 8; ++ks) {
          bf16x8 a = *(const bf16x8*)&Xs[(size_t)(16 * mk + ln) * 264 + ks * 32 + quad * 8];
          acc = __builtin_amdgcn_mfma_f32_16x16x32_bf16(a, bw[ks], acc, 0, 0, 0);
        }
        int kl = 16 * mk + quad * 4;
        #pragma unroll
        for (int r = 0; r < 4; ++r) {    // xpos downscale, write K row-major
          float v = acc[r];
          float pv = __shfl_xor(v, 1, 64);
          int p = k0g + kl + r;
          int tp = (p < L_SEQ) ? p : (L_SEQ - 1);
          float cc = cd[tp * 128 + hn], ss = sd[tp * 128 + hn];
          float okk = (dn & 1) ? (v * cc + pv * ss) : (v * cc - pv * ss);
          Ks[(size_t)(kl + r) * 264 + dn] = f2bf(okk);
        }
      }
      #pragma unroll
      for (int ks = 0; ks < 8; ++ks)
        bw[ks] = *(const bf16x8*)(Wt + (size_t)(512 + dn) * 256 + ks * 32 + quad * 8);
      for (int mk = 0; mk < 6; ++mk) {
        f32x4 acc = {};
        #pragma unroll
        for (int ks = 0; ks < 8; ++ks) {
          bf16x8 a = *(const bf16x8*)&Xs[(size_t)(16 * mk + ln) * 264 + ks * 32 + quad * 8];
          acc = __builtin_amdgcn_mfma_f32_16x16x32_bf16(a, bw[ks], acc, 0, 0, 0);
        }
        int kl = 16 * mk + quad * 4;
        #pragma unroll
        for (int r = 0; r < 4; ++r)      // V transposed: Vs[d][key_local]
          Vs[(size_t)dn * 104 + kl + r] = f2bf(acc[r]);
      }
    }
    __syncthreads();                     // E: Ks/Vs ready; Xs dead -> Pw usable
    if (cp1 >= c) {
      // per-row key limit for this chunk: min(causal-chunk lim, home-chunk end)
      int limc[2][4];
      #pragma unroll
      for (int t = 0; t < 2; ++t)
        #pragma unroll
        for (int r = 0; r < 4; ++r) {
          int i = rowbase + 16 * t + quad * 4 + r;
          int l = (i / CHK + 1) * CHK;
          if (l > L_SEQ) l = L_SEQ;
          int ce = k0g + CHK;
          limc[t][r] = (l < ce) ? l : ce;
        }
      #pragma unroll
      for (int ksl = 0; ksl < 3; ++ksl) {
        // S = Q K^T for 32 keys (2 ksubs)
        f32x4 s0[2] = {}, s1[2] = {};
        #pragma unroll
        for (int kk = 0; kk < 2; ++kk) {
          #pragma unroll
          for (int ks = 0; ks < 8; ++ks) {
            bf16x8 bk = *(const bf16x8*)&Ks[(size_t)(ksl * 32 + kk * 16 + ln) * 264 + ks * 32 + quad * 8];
            s0[kk] = __builtin_amdgcn_mfma_f32_16x16x32_bf16(qreg[0][ks], bk, s0[kk], 0, 0, 0);
            s1[kk] = __builtin_amdgcn_mfma_f32_16x16x32_bf16(qreg[1][ks], bk, s1[kk], 0, 0, 0);
          }
        }
        // decay in fp32, P -> bf16 -> wave-private bounce (ds in-order per wave)
        #pragma unroll
        for (int kk = 0; kk < 2; ++kk) {
          int m = k0g + ksl * 32 + kk * 16 + ln;   // global key
          #pragma unroll
          for (int r = 0; r < 4; ++r) {
            { int i = rowbase + quad * 4 + r;
              int ad = i - m; ad = (ad < 0) ? -ad : ad; if (ad > 255) ad = 255;
              float f = (m < limc[0][r]) ? gps[ad] : 0.0f;
              Pw[(quad * 4 + r) * 40 + kk * 16 + ln] = f2bf(s0[kk][r] * f); }
            { int i = rowbase + 16 + quad * 4 + r;
              int ad = i - m; ad = (ad < 0) ? -ad : ad; if (ad > 255) ad = 255;
              float f = (m < limc[1][r]) ? gps[ad] : 0.0f;
              Pw[(16 + quad * 4 + r) * 40 + kk * 16 + ln] = f2bf(s1[kk][r] * f); }
          }
        }
        bf16x8 ap0 = *(const bf16x8*)&Pw[(0  + ln) * 40 + quad * 8];
        bf16x8 ap1 = *(const bf16x8*)&Pw[(16 + ln) * 40 + quad * 8];
        // O += P V
        #pragma unroll
        for (int nt = 0; nt < 16; ++nt) {
          bf16x8 bv = *(const bf16x8*)&Vs[(size_t)(16 * nt + ln) * 104 + ksl * 32 + quad * 8];
          o[0][nt] = __builtin_amdgcn_mfma_f32_16x16x32_bf16(ap0, bv, o[0][nt], 0, 0, 0);
          o[1][nt] = __builtin_amdgcn_mfma_f32_16x16x32_bf16(ap1, bv, o[1][nt], 0, 0, 0);
        }
      }
    }
  }
  // ---- epilogue: fp32 store (nontemporal; keep L2 for Wt/tables) ----
  #pragma unroll
  for (int t = 0; t < 2; ++t)
    #pragma unroll
    for (int nt = 0; nt < 16; ++nt) {
      int d = 16 * nt + ln;
      #pragma unroll
      for (int r = 0; r < 4; ++r) {
        int p = rowbase + 16 * t + quad * 4 + r;
        if (p < L_SEQ)
          __builtin_nontemporal_store(o[t][nt][r], Out + ((size_t)b * L_SEQ + p) * 256 + d);
      }
    }
}

extern "C" void kernel_launch(void* const* d_in, const int* in_sizes, int n_in,
                              void* d_out, int out_size, void* d_ws, size_t ws_size,
                              hipStream_t stream) {
  const float* X     = (const float*)d_in[0];
  const float* Wq    = (const float*)d_in[1];
  const float* Wk    = (const float*)d_in[2];
  const float* Wv    = (const float*)d_in[3];
  const float* gamma = (const float*)d_in[4];
  if (ws_size < WS_NEED) return;  // deterministic guard (same work every call)

  char* ws = (char*)d_ws;
  unsigned short* Wt  = (unsigned short*)(ws + OFF_WT);
  float* cu = (float*)(ws + OFF_TAB);
  float* su = cu + L_SEQ * 128;
  float* cd = su + L_SEQ * 128;
  float* sd = cd + L_SEQ * 128;
  float* gp = (float*)(ws + OFF_GP);

  hipLaunchKernelGGL(prep_kernel, dim3(907), dim3(256), 0, stream,
                     Wq, Wk, Wv, gamma, Wt, cu, su, cd, sd, gp);
  hipLaunchKernelGGL(fused_kernel, dim3(NB), dim3(512), 0, stream,
                     X, Wt, cu, su, cd, sd, gp, (float*)d_out);
}